// Round 7
// baseline (444.389 us; speedup 1.0000x reference)
//
#include <hip/hip_runtime.h>
#include <stdint.h>

#define N 8192
#define IN_F 512
#define OUT_F 128
#define NCLS 10
#define ALPHA 0.2f

typedef float f32x4 __attribute__((ext_vector_type(4)));
typedef int   i32x4 __attribute__((ext_vector_type(4)));
typedef short s16x4 __attribute__((ext_vector_type(4)));
typedef short s16x8 __attribute__((ext_vector_type(8)));

__device__ __forceinline__ short f2bf(float x) {
    unsigned u = __builtin_bit_cast(unsigned, x);
    u = (u + 0x7FFFu + ((u >> 16) & 1u)) >> 16;  // RNE
    return (short)u;
}
__device__ __forceinline__ float bf2f(short s) {
    unsigned u = ((unsigned)(unsigned short)s) << 16;
    return __builtin_bit_cast(float, u);
}

// ---------------------------------------------------------------------------
// Kernel M: dist (int32 0/1, 268 MB) -> 1-bit adjacency mask (8 MB).
// Pure streaming: 128 B contiguous read + 4 B write per thread. ONLY reader
// of dist. Word w covers row i = w/256, j in [(w%256)*32, +32); bit = j%32.
// ---------------------------------------------------------------------------
__global__ __launch_bounds__(256, 8)
void mask_kernel(const int* __restrict__ dist, unsigned* __restrict__ mask) {
    size_t w = (size_t)blockIdx.x * 256 + threadIdx.x;   // 8192*256 words
    const int* p = dist + w * 32;
    unsigned b = 0;
    #pragma unroll
    for (int u = 0; u < 8; ++u) {
        i32x4 v = *(const i32x4*)(p + u * 4);
        #pragma unroll
        for (int e = 0; e < 4; ++e) b |= (v[e] > 0 ? 1u : 0u) << (u * 4 + e);
    }
    mask[w] = b;
}

// ---------------------------------------------------------------------------
// Kernel 0: split W [512][128] fp32 -> bf16 hi/lo in fragment-blocked layout:
// idx(col,k) = (k>>5)*(128*32) + col*32 + (k&31)
// ---------------------------------------------------------------------------
__global__ void split_w_kernel(const float* __restrict__ W,
                               short* __restrict__ WThi, short* __restrict__ WTlo) {
    int idx = blockIdx.x * 256 + threadIdx.x;       // 512*128 = 65536
    int k = idx >> 7, col = idx & 127;
    float x = W[idx];                               // row-major [k][col]
    short hi = f2bf(x);
    short lo = f2bf(x - bf2f(hi));
    size_t a = (size_t)(k >> 5) * (128 * 32) + (size_t)col * 32 + (k & 31);
    WThi[a] = hi;
    WTlo[a] = lo;
}

// ---------------------------------------------------------------------------
// Kernel 1: Wh = h@W via split-bf16 MFMA (3 products). Writes Wh1/Wh2 (fp32)
// and WhT bf16 fragment-blocked [(j>>5)][col][j&31].
// 512 blocks x 256 threads, 16 rows/block.
// ---------------------------------------------------------------------------
#define WH_ROWS 16
#define WH_STR 520   // 512 + 8 shorts pad: frag reads land 2-way (free)

__global__ __launch_bounds__(256, 2)
void wh_kernel(const float* __restrict__ h, const short* __restrict__ WThi,
               const short* __restrict__ WTlo, const float* __restrict__ a,
               short* __restrict__ WhT, float* __restrict__ Wh1,
               float* __restrict__ Wh2) {
    __shared__ __align__(16) short Ahi[WH_ROWS][WH_STR];
    __shared__ __align__(16) short Alo[WH_ROWS][WH_STR];
    __shared__ __align__(16) float whs[WH_ROWS][OUT_F + 4];

    const int t = threadIdx.x;
    const int r0 = blockIdx.x * WH_ROWS;

    {   // stage h tile [16][512] as bf16 hi/lo (coalesced 32B/lane reads)
        int row = t >> 4, c4 = t & 15;
        const float* hrow = h + (size_t)(r0 + row) * IN_F;
        #pragma unroll
        for (int jj = 0; jj < 4; ++jj) {
            int k0 = c4 * 8 + jj * 128;
            f32x4 x0 = *(const f32x4*)(hrow + k0);
            f32x4 x1 = *(const f32x4*)(hrow + k0 + 4);
            s16x8 hi, lo;
            #pragma unroll
            for (int e = 0; e < 4; ++e) {
                short h0 = f2bf(x0[e]); hi[e] = h0; lo[e] = f2bf(x0[e] - bf2f(h0));
                short h1 = f2bf(x1[e]); hi[4 + e] = h1; lo[4 + e] = f2bf(x1[e] - bf2f(h1));
            }
            *(s16x8*)&Ahi[row][k0] = hi;
            *(s16x8*)&Alo[row][k0] = lo;
        }
    }
    __syncthreads();

    const int lane = t & 63, w = t >> 6;
    const int q = lane >> 4, ln16 = lane & 15;
    f32x4 acc[2] = {};
    #pragma unroll
    for (int kc = 0; kc < IN_F / 32; ++kc) {
        s16x8 ahi = *(const s16x8*)&Ahi[ln16][kc * 32 + q * 8];
        s16x8 alo = *(const s16x8*)&Alo[ln16][kc * 32 + q * 8];
        #pragma unroll
        for (int nt = 0; nt < 2; ++nt) {
            int col = w * 32 + nt * 16 + ln16;
            size_t boff = (size_t)kc * 4096 + (size_t)col * 32 + q * 8;
            s16x8 bhi = *(const s16x8*)(WThi + boff);
            s16x8 blo = *(const s16x8*)(WTlo + boff);
            acc[nt] = __builtin_amdgcn_mfma_f32_16x16x32_bf16(ahi, bhi, acc[nt], 0, 0, 0);
            acc[nt] = __builtin_amdgcn_mfma_f32_16x16x32_bf16(ahi, blo, acc[nt], 0, 0, 0);
            acc[nt] = __builtin_amdgcn_mfma_f32_16x16x32_bf16(alo, bhi, acc[nt], 0, 0, 0);
        }
    }
    #pragma unroll
    for (int nt = 0; nt < 2; ++nt)
        #pragma unroll
        for (int reg = 0; reg < 4; ++reg)
            whs[q * 4 + reg][w * 32 + nt * 16 + ln16] = acc[nt][reg];
    __syncthreads();

    // Wh1/Wh2: 16 rows, 8 threads per row
    if (t < 128) {
        int r = t >> 3, s = t & 7;
        float s1 = 0.f, s2 = 0.f;
        #pragma unroll
        for (int cc = 0; cc < 16; ++cc) {
            int c = s * 16 + cc;
            float v = whs[r][c];
            s1 = fmaf(v, a[c], s1);
            s2 = fmaf(v, a[OUT_F + c], s2);
        }
        s1 += __shfl_xor(s1, 1); s1 += __shfl_xor(s1, 2); s1 += __shfl_xor(s1, 4);
        s2 += __shfl_xor(s2, 1); s2 += __shfl_xor(s2, 2); s2 += __shfl_xor(s2, 4);
        if (s == 0) { Wh1[r0 + r] = s1; Wh2[r0 + r] = s2; }
    }

    // WhT bf16, fragment-blocked: idx = (j>>5)*4096 + col*32 + (j&31)
    {
        int c = t >> 1, h8 = t & 1;
        s16x8 pack;
        #pragma unroll
        for (int rr = 0; rr < 8; ++rr) pack[rr] = f2bf(whs[h8 * 8 + rr][c]);
        size_t addr = (size_t)(r0 >> 5) * 4096 + (size_t)c * 32 + (r0 & 16) + h8 * 8;
        *(s16x8*)(WhT + addr) = pack;
    }
}

// ---------------------------------------------------------------------------
// Kernel 2 (v7): r2's LDS-P attention + cross-iteration register pipelining.
// Identical geometry to r2 (BK=256, 4 blocks/CU, 8 barriers); the ONLY change:
// Wh2 (8 x f32x4) and mask (2 x i32x4) for iteration kt+1 are loaded into a
// second register buffer BEFORE the barrier of iteration kt, so their latency
// hides under sync+mfma. kt-loop fully unrolled (x2) -> static buffer indexing.
// ---------------------------------------------------------------------------
#define BM 32
#define BK 256
#define ASTR (BK + 8)
#define SPLIT 4
#define NIT (N / (BK * SPLIT))   // 8

__device__ __forceinline__ f32x4 mfma16(s16x8 a, s16x8 b, f32x4 c) {
    return __builtin_amdgcn_mfma_f32_16x16x32_bf16(a, b, c, 0, 0, 0);
}

__device__ __forceinline__ void pphase(const f32x4 (&wb)[8], i32x4 m0, i32x4 m1,
                                       short* arow, int sh, float wh1,
                                       float& l_acc) {
    #pragma unroll
    for (int u = 0; u < 8; ++u) {
        f32x4 w2 = wb[u];
        unsigned wrd = (unsigned)((u < 4) ? m0[u] : m1[u - 4]);
        unsigned nib = (wrd >> sh) & 15u;
        s16x4 pk;
        #pragma unroll
        for (int e = 0; e < 4; ++e) {
            float sv = wh1 + w2[e];
            float lr = fmaxf(sv, ALPHA * sv);
            float pv = (nib & (1u << e)) ? __expf(lr) : 0.f;
            l_acc += pv;
            pk[e] = f2bf(pv);
        }
        *(s16x4*)(arow + u * 32 + sh) = pk;
    }
}

__device__ __forceinline__ void mfmaphase(const short* ab, const short* bbase,
                                          int ln16, int q, int w,
                                          f32x4 (&acc)[2][2]) {
    #pragma unroll
    for (int kc = 0; kc < BK / 32; ++kc) {
        s16x8 a0 = *(const s16x8*)(ab + ln16 * ASTR + kc * 32 + q * 8);
        s16x8 a1 = *(const s16x8*)(ab + (16 + ln16) * ASTR + kc * 32 + q * 8);
        #pragma unroll
        for (int nt = 0; nt < 2; ++nt) {
            int col = w * 32 + nt * 16 + ln16;
            s16x8 b = *(const s16x8*)(bbase + (size_t)kc * 4096 + col * 32 + q * 8);
            acc[0][nt] = mfma16(a0, b, acc[0][nt]);
            acc[1][nt] = mfma16(a1, b, acc[1][nt]);
        }
    }
}

__global__ __launch_bounds__(256, 4)
void attn_kernel(const unsigned* __restrict__ mask, const short* __restrict__ WhT,
                 const float* __restrict__ Wh1v, const float* __restrict__ Wh2v,
                 float* __restrict__ acc_part, float* __restrict__ l_part) {
    __shared__ __align__(16) short As[2][BM][ASTR];

    const int t = threadIdx.x;
    const int it = blockIdx.x & 255;
    const int sp = blockIdx.x >> 8;
    const int i0 = it * BM;
    const int r = t >> 3, s = t & 7;       // p-phase: row r, j-slice s
    const int lane = t & 63, w = t >> 6;   // mfma-phase
    const int q = lane >> 4, ln16 = lane & 15;
    const int j0 = sp * (NIT * BK);
    const int sh = s * 4;

    const unsigned* __restrict__ mrow = mask + (size_t)(i0 + r) * (N / 32) + (j0 >> 5);
    const float* __restrict__ wh2p = Wh2v + j0 + sh;
    const float wh1 = Wh1v[i0 + r];
    float l_acc = 0.f;
    f32x4 acc[2][2] = {};

    f32x4 wbA[8], wbB[8];
    i32x4 mA0, mA1, mB0, mB1;

    // preload iteration 0
    #pragma unroll
    for (int u = 0; u < 8; ++u) wbA[u] = *(const f32x4*)(wh2p + u * 32);
    mA0 = *(const i32x4*)(mrow);
    mA1 = *(const i32x4*)(mrow + 4);

    #pragma unroll
    for (int kt2 = 0; kt2 < NIT / 2; ++kt2) {
        const int kt = 2 * kt2;
        // ---- even iteration kt ----
        pphase(wbA, mA0, mA1, &As[0][r][0], sh, wh1, l_acc);
        {   // prefetch kt+1 (flies under sync + mfma)
            #pragma unroll
            for (int u = 0; u < 8; ++u)
                wbB[u] = *(const f32x4*)(wh2p + (kt + 1) * BK + u * 32);
            mB0 = *(const i32x4*)(mrow + (kt + 1) * 8);
            mB1 = *(const i32x4*)(mrow + (kt + 1) * 8 + 4);
        }
        __syncthreads();
        mfmaphase(&As[0][0][0], WhT + (size_t)(j0 + kt * BK) * 128, ln16, q, w, acc);

        // ---- odd iteration kt+1 ----
        pphase(wbB, mB0, mB1, &As[1][r][0], sh, wh1, l_acc);
        if (kt2 + 1 < NIT / 2) {   // prefetch kt+2
            #pragma unroll
            for (int u = 0; u < 8; ++u)
                wbA[u] = *(const f32x4*)(wh2p + (kt + 2) * BK + u * 32);
            mA0 = *(const i32x4*)(mrow + (kt + 2) * 8);
            mA1 = *(const i32x4*)(mrow + (kt + 2) * 8 + 4);
        }
        __syncthreads();
        mfmaphase(&As[1][0][0], WhT + (size_t)(j0 + (kt + 1) * BK) * 128, ln16, q, w, acc);
    }

    // partial row sums
    l_acc += __shfl_xor(l_acc, 1);
    l_acc += __shfl_xor(l_acc, 2);
    l_acc += __shfl_xor(l_acc, 4);
    if (s == 0) l_part[(size_t)sp * N + i0 + r] = l_acc;

    // partial acc (C/D: col=lane&15, row=q*4+reg)
    float* ap = acc_part + (size_t)sp * N * OUT_F + (size_t)i0 * OUT_F;
    #pragma unroll
    for (int mt = 0; mt < 2; ++mt)
        #pragma unroll
        for (int reg = 0; reg < 4; ++reg) {
            int row = mt * 16 + q * 4 + reg;
            #pragma unroll
            for (int nt = 0; nt < 2; ++nt)
                ap[(size_t)row * OUT_F + w * 32 + nt * 16 + ln16] = acc[mt][nt][reg];
        }
}

// ---------------------------------------------------------------------------
// Kernel 3: reduce partials, softmax-divide, elu, classifier.
// 512 blocks x 256 threads, 16 rows/block.
// ---------------------------------------------------------------------------
__global__ __launch_bounds__(256, 4)
void reduce_kernel(const float* __restrict__ acc_part, const float* __restrict__ l_part,
                   const float* __restrict__ Wc, const float* __restrict__ bcv,
                   float* __restrict__ out, int split) {
    __shared__ __align__(16) float hu[16][OUT_F + 4];
    const int t = threadIdx.x;
    const int i0 = blockIdx.x * 16;
    const int row = t >> 4, cg = t & 15;

    f32x4 v0 = {0.f, 0.f, 0.f, 0.f}, v1 = {0.f, 0.f, 0.f, 0.f};
    float l = 0.f;
    for (int s = 0; s < split; ++s) {
        const float* ap = acc_part + (size_t)s * N * OUT_F + (size_t)(i0 + row) * OUT_F + cg * 8;
        v0 += *(const f32x4*)ap;
        v1 += *(const f32x4*)(ap + 4);
        l += l_part[(size_t)s * N + i0 + row];
    }
    float inv = 1.f / l;
    #pragma unroll
    for (int e = 0; e < 4; ++e) {
        float x0 = v0[e] * inv; x0 = x0 > 0.f ? x0 : (__expf(x0) - 1.f);
        float x1 = v1[e] * inv; x1 = x1 > 0.f ? x1 : (__expf(x1) - 1.f);
        hu[row][cg * 8 + e] = x0;
        hu[row][cg * 8 + 4 + e] = x1;
    }
    __syncthreads();

    if (t < 16 * NCLS) {
        int rr = t / NCLS, cls = t - rr * NCLS;
        const f32x4* hurow = (const f32x4*)&hu[rr][0];
        const f32x4* wcrow = (const f32x4*)(Wc + cls * OUT_F);
        float sum = bcv[cls];
        #pragma unroll 8
        for (int c4 = 0; c4 < OUT_F / 4; ++c4) {
            f32x4 hv = hurow[c4];
            f32x4 wv = wcrow[c4];
            sum += hv[0] * wv[0] + hv[1] * wv[1] + hv[2] * wv[2] + hv[3] * wv[3];
        }
        out[(size_t)(i0 + rr) * NCLS + cls] = sum;
    }
}

// ---------------------------------------------------------------------------
extern "C" void kernel_launch(void* const* d_in, const int* in_sizes, int n_in,
                              void* d_out, int out_size, void* d_ws, size_t ws_size,
                              hipStream_t stream) {
    const float* h    = (const float*)d_in[0];
    const int*   dist = (const int*)d_in[1];
    const float* W    = (const float*)d_in[2];
    const float* a    = (const float*)d_in[3];
    const float* Wc   = (const float*)d_in[4];
    const float* bc   = (const float*)d_in[5];
    float* out = (float*)d_out;

    char* ws = (char*)d_ws;
    size_t off = 0;
    short* WhT  = (short*)(ws + off); off += (size_t)OUT_F * N * 2;     // 2 MB
    short* WThi = (short*)(ws + off); off += (size_t)IN_F * OUT_F * 2;  // 128 KB
    short* WTlo = (short*)(ws + off); off += (size_t)IN_F * OUT_F * 2;  // 128 KB
    float* Wh1  = (float*)(ws + off); off += (size_t)N * 4;
    float* Wh2  = (float*)(ws + off); off += (size_t)N * 4;
    unsigned* mask = (unsigned*)(ws + off); off += (size_t)N * (N / 32) * 4; // 8 MB

    float* acc_part = (float*)(ws + off); off += (size_t)SPLIT * N * OUT_F * 4; // 16 MB
    float* l_part   = (float*)(ws + off);

    hipLaunchKernelGGL(mask_kernel, dim3(N * (N / 32) / 256), dim3(256), 0, stream,
                       dist, mask);
    hipLaunchKernelGGL(split_w_kernel, dim3(256), dim3(256), 0, stream, W, WThi, WTlo);
    hipLaunchKernelGGL(wh_kernel, dim3(N / WH_ROWS), dim3(256), 0, stream,
                       h, WThi, WTlo, a, WhT, Wh1, Wh2);
    hipLaunchKernelGGL(attn_kernel, dim3(256 * SPLIT), dim3(256), 0, stream,
                       mask, WhT, Wh1, Wh2, acc_part, l_part);
    hipLaunchKernelGGL(reduce_kernel, dim3(N / 16), dim3(256), 0, stream,
                       acc_part, l_part, Wc, bc, out, SPLIT);
}

// Round 8
// 438.237 us; speedup vs baseline: 1.0140x; 1.0140x over previous
//
#include <hip/hip_runtime.h>
#include <stdint.h>

#define N 8192
#define IN_F 512
#define OUT_F 128
#define NCLS 10
#define ALPHA 0.2f
#define LOG2E 1.44269504088896340736f

typedef float f32x4 __attribute__((ext_vector_type(4)));
typedef int   i32x4 __attribute__((ext_vector_type(4)));
typedef short s16x4 __attribute__((ext_vector_type(4)));
typedef short s16x8 __attribute__((ext_vector_type(8)));
typedef unsigned u32x2 __attribute__((ext_vector_type(2)));

__device__ __forceinline__ short f2bf(float x) {
    unsigned u = __builtin_bit_cast(unsigned, x);
    u = (u + 0x7FFFu + ((u >> 16) & 1u)) >> 16;  // RNE
    return (short)u;
}
__device__ __forceinline__ float bf2f(short s) {
    unsigned u = ((unsigned)(unsigned short)s) << 16;
    return __builtin_bit_cast(float, u);
}

// ---------------------------------------------------------------------------
// Kernel M: dist (int32 0/1, 268 MB) -> 1-bit adjacency mask (8 MB).
// Pure streaming; ONLY reader of dist. Word w covers row i = w/256,
// j in [(w%256)*32, +32); bit = j%32.
// ---------------------------------------------------------------------------
__global__ __launch_bounds__(256, 8)
void mask_kernel(const int* __restrict__ dist, unsigned* __restrict__ mask) {
    size_t w = (size_t)blockIdx.x * 256 + threadIdx.x;   // 8192*256 words
    const int* p = dist + w * 32;
    unsigned b = 0;
    #pragma unroll
    for (int u = 0; u < 8; ++u) {
        i32x4 v = *(const i32x4*)(p + u * 4);
        #pragma unroll
        for (int e = 0; e < 4; ++e) b |= (v[e] > 0 ? 1u : 0u) << (u * 4 + e);
    }
    mask[w] = b;
}

// ---------------------------------------------------------------------------
// Kernel 0: split W [512][128] fp32 -> bf16 hi/lo in fragment-blocked layout:
// idx(col,k) = (k>>5)*(128*32) + col*32 + (k&31)
// ---------------------------------------------------------------------------
__global__ void split_w_kernel(const float* __restrict__ W,
                               short* __restrict__ WThi, short* __restrict__ WTlo) {
    int idx = blockIdx.x * 256 + threadIdx.x;       // 512*128 = 65536
    int k = idx >> 7, col = idx & 127;
    float x = W[idx];                               // row-major [k][col]
    short hi = f2bf(x);
    short lo = f2bf(x - bf2f(hi));
    size_t a = (size_t)(k >> 5) * (128 * 32) + (size_t)col * 32 + (k & 31);
    WThi[a] = hi;
    WTlo[a] = lo;
}

// ---------------------------------------------------------------------------
// Kernel 1: Wh = h@W via split-bf16 MFMA (3 products). Writes Wh1/Wh2 (fp32,
// PRE-SCALED by log2e: attn uses exp2 directly) and WhT bf16 fragment-blocked.
// 512 blocks x 256 threads, 16 rows/block.
// ---------------------------------------------------------------------------
#define WH_ROWS 16
#define WH_STR 520   // 512 + 8 shorts pad: frag reads land 2-way (free)

__global__ __launch_bounds__(256, 2)
void wh_kernel(const float* __restrict__ h, const short* __restrict__ WThi,
               const short* __restrict__ WTlo, const float* __restrict__ a,
               short* __restrict__ WhT, float* __restrict__ Wh1,
               float* __restrict__ Wh2) {
    __shared__ __align__(16) short Ahi[WH_ROWS][WH_STR];
    __shared__ __align__(16) short Alo[WH_ROWS][WH_STR];
    __shared__ __align__(16) float whs[WH_ROWS][OUT_F + 4];

    const int t = threadIdx.x;
    const int r0 = blockIdx.x * WH_ROWS;

    {   // stage h tile [16][512] as bf16 hi/lo (coalesced 32B/lane reads)
        int row = t >> 4, c4 = t & 15;
        const float* hrow = h + (size_t)(r0 + row) * IN_F;
        #pragma unroll
        for (int jj = 0; jj < 4; ++jj) {
            int k0 = c4 * 8 + jj * 128;
            f32x4 x0 = *(const f32x4*)(hrow + k0);
            f32x4 x1 = *(const f32x4*)(hrow + k0 + 4);
            s16x8 hi, lo;
            #pragma unroll
            for (int e = 0; e < 4; ++e) {
                short h0 = f2bf(x0[e]); hi[e] = h0; lo[e] = f2bf(x0[e] - bf2f(h0));
                short h1 = f2bf(x1[e]); hi[4 + e] = h1; lo[4 + e] = f2bf(x1[e] - bf2f(h1));
            }
            *(s16x8*)&Ahi[row][k0] = hi;
            *(s16x8*)&Alo[row][k0] = lo;
        }
    }
    __syncthreads();

    const int lane = t & 63, w = t >> 6;
    const int q = lane >> 4, ln16 = lane & 15;
    f32x4 acc[2] = {};
    #pragma unroll
    for (int kc = 0; kc < IN_F / 32; ++kc) {
        s16x8 ahi = *(const s16x8*)&Ahi[ln16][kc * 32 + q * 8];
        s16x8 alo = *(const s16x8*)&Alo[ln16][kc * 32 + q * 8];
        #pragma unroll
        for (int nt = 0; nt < 2; ++nt) {
            int col = w * 32 + nt * 16 + ln16;
            size_t boff = (size_t)kc * 4096 + (size_t)col * 32 + q * 8;
            s16x8 bhi = *(const s16x8*)(WThi + boff);
            s16x8 blo = *(const s16x8*)(WTlo + boff);
            acc[nt] = __builtin_amdgcn_mfma_f32_16x16x32_bf16(ahi, bhi, acc[nt], 0, 0, 0);
            acc[nt] = __builtin_amdgcn_mfma_f32_16x16x32_bf16(ahi, blo, acc[nt], 0, 0, 0);
            acc[nt] = __builtin_amdgcn_mfma_f32_16x16x32_bf16(alo, bhi, acc[nt], 0, 0, 0);
        }
    }
    #pragma unroll
    for (int nt = 0; nt < 2; ++nt)
        #pragma unroll
        for (int reg = 0; reg < 4; ++reg)
            whs[q * 4 + reg][w * 32 + nt * 16 + ln16] = acc[nt][reg];
    __syncthreads();

    // Wh1/Wh2: 16 rows, 8 threads per row (stored pre-scaled by log2e;
    // max(s*x, alpha*s*x) = s*max(x, alpha*x) for s>0, so leakyrelu commutes)
    if (t < 128) {
        int r = t >> 3, s = t & 7;
        float s1 = 0.f, s2 = 0.f;
        #pragma unroll
        for (int cc = 0; cc < 16; ++cc) {
            int c = s * 16 + cc;
            float v = whs[r][c];
            s1 = fmaf(v, a[c], s1);
            s2 = fmaf(v, a[OUT_F + c], s2);
        }
        s1 += __shfl_xor(s1, 1); s1 += __shfl_xor(s1, 2); s1 += __shfl_xor(s1, 4);
        s2 += __shfl_xor(s2, 1); s2 += __shfl_xor(s2, 2); s2 += __shfl_xor(s2, 4);
        if (s == 0) { Wh1[r0 + r] = s1 * LOG2E; Wh2[r0 + r] = s2 * LOG2E; }
    }

    // WhT bf16, fragment-blocked: idx = (j>>5)*4096 + col*32 + (j&31)
    {
        int c = t >> 1, h8 = t & 1;
        s16x8 pack;
        #pragma unroll
        for (int rr = 0; rr < 8; ++rr) pack[rr] = f2bf(whs[h8 * 8 + rr][c]);
        size_t addr = (size_t)(r0 >> 5) * 4096 + (size_t)c * 32 + (r0 & 16) + h8 * 8;
        *(s16x8*)(WhT + addr) = pack;
    }
}

// ---------------------------------------------------------------------------
// Kernel 2 (v8): r2's LDS-P attention with a slimmed p-phase VALU core:
//  - v_cvt_pk_bf16_f32 (HW RNE, 1 instr/2 scores) replaces 4-op manual RNE
//  - inputs pre-scaled by log2e -> bare v_exp (exp2), no per-score mul
//  - row-sum l computed by a ones-column MFMA on waves 0/1 (MFMA pipe is
//    ~3% busy -> free), deleting the per-score l_acc add + shuffle reduce
// Geometry identical to r2: BK=256, dbuf As, 1 barrier/iter, 4 blocks/CU.
// ---------------------------------------------------------------------------
#define BM 32
#define BK 256
#define ASTR (BK + 8)
#define SPLIT 4
#define NIT (N / (BK * SPLIT))   // 8

__device__ __forceinline__ f32x4 mfma16(s16x8 a, s16x8 b, f32x4 c) {
    return __builtin_amdgcn_mfma_f32_16x16x32_bf16(a, b, c, 0, 0, 0);
}

__global__ __launch_bounds__(256, 4)
void attn_kernel(const unsigned* __restrict__ mask, const short* __restrict__ WhT,
                 const float* __restrict__ Wh1v, const float* __restrict__ Wh2v,
                 float* __restrict__ acc_part, float* __restrict__ l_part) {
    __shared__ __align__(16) short As[2][BM][ASTR];

    const int t = threadIdx.x;
    const int it = blockIdx.x & 255;
    const int sp = blockIdx.x >> 8;
    const int i0 = it * BM;
    const int r = t >> 3, s = t & 7;       // p-phase: row r, j-slice s
    const int lane = t & 63, w = t >> 6;   // mfma-phase
    const int q = lane >> 4, ln16 = lane & 15;
    const int j0 = sp * (NIT * BK);
    const int sh = s * 4;

    const unsigned* __restrict__ mrow = mask + (size_t)(i0 + r) * (N / 32) + (j0 >> 5);
    const float* __restrict__ wh2p = Wh2v + j0;
    const float wh1 = Wh1v[i0 + r];
    f32x4 acc[2][2] = {};
    f32x4 accl = {};                       // ones-column row sums (waves 0,1)

    s16x8 bones;
    #pragma unroll
    for (int e = 0; e < 8; ++e) bones[e] = (short)0x3F80;   // bf16(1.0)

    i32x4 m0 = *(const i32x4*)(mrow);
    i32x4 m1 = *(const i32x4*)(mrow + 4);

    for (int kt = 0; kt < NIT; ++kt) {
        const int jb = kt * BK;
        const bool more = (kt + 1) < NIT;
        i32x4 n0, n1;
        if (more) {
            n0 = *(const i32x4*)(mrow + (kt + 1) * 8);
            n1 = *(const i32x4*)(mrow + (kt + 1) * 8 + 4);
        }
        short* arow = &As[kt & 1][r][0];
        #pragma unroll
        for (int u = 0; u < 8; ++u) {
            f32x4 w2 = *(const f32x4*)(wh2p + jb + u * 32 + sh);
            unsigned wrd = (u < 4) ? (unsigned)m0[u] : (unsigned)m1[u - 4];
            unsigned nib = (wrd >> sh) & 15u;
            float p[4];
            #pragma unroll
            for (int e = 0; e < 4; ++e) {
                float sv = wh1 + w2[e];                  // already x log2e
                float lr = fmaxf(sv, ALPHA * sv);
                float ev = __builtin_amdgcn_exp2f(lr);   // = exp(score)
                p[e] = (nib & (1u << e)) ? ev : 0.f;
            }
            unsigned pk01, pk23;
            asm("v_cvt_pk_bf16_f32 %0, %1, %2" : "=v"(pk01) : "v"(p[0]), "v"(p[1]));
            asm("v_cvt_pk_bf16_f32 %0, %1, %2" : "=v"(pk23) : "v"(p[2]), "v"(p[3]));
            u32x2 pk = {pk01, pk23};
            *(u32x2*)(arow + u * 32 + sh) = pk;
        }
        __syncthreads();
        const short* ab = &As[kt & 1][0][0];
        const short* bbase = WhT + (size_t)(j0 + jb) * 128;   // blocked layout
        #pragma unroll
        for (int kc = 0; kc < BK / 32; ++kc) {
            s16x8 a0 = *(const s16x8*)(ab + ln16 * ASTR + kc * 32 + q * 8);
            s16x8 a1 = *(const s16x8*)(ab + (16 + ln16) * ASTR + kc * 32 + q * 8);
            if (w == 0) accl = mfma16(a0, bones, accl);   // rows 0..15 sums
            if (w == 1) accl = mfma16(a1, bones, accl);   // rows 16..31 sums
            #pragma unroll
            for (int nt = 0; nt < 2; ++nt) {
                int col = w * 32 + nt * 16 + ln16;
                s16x8 b = *(const s16x8*)(bbase + (size_t)kc * 4096 + col * 32 + q * 8);
                acc[0][nt] = mfma16(a0, b, acc[0][nt]);
                acc[1][nt] = mfma16(a1, b, acc[1][nt]);
            }
        }
        if (more) { m0 = n0; m1 = n1; }
    }

    // l: C/D col=ln16 (duplicated), row = q*4+reg; wave0 rows 0-15, wave1 16-31
    if (w < 2 && ln16 == 0) {
        #pragma unroll
        for (int reg = 0; reg < 4; ++reg)
            l_part[(size_t)sp * N + i0 + w * 16 + q * 4 + reg] = accl[reg];
    }

    // partial acc (C/D: col=lane&15, row=q*4+reg)
    float* ap = acc_part + (size_t)sp * N * OUT_F + (size_t)i0 * OUT_F;
    #pragma unroll
    for (int mt = 0; mt < 2; ++mt)
        #pragma unroll
        for (int reg = 0; reg < 4; ++reg) {
            int row = mt * 16 + q * 4 + reg;
            #pragma unroll
            for (int nt = 0; nt < 2; ++nt)
                ap[(size_t)row * OUT_F + w * 32 + nt * 16 + ln16] = acc[mt][nt][reg];
        }
}

// ---------------------------------------------------------------------------
// Kernel 3: reduce partials, softmax-divide, elu, classifier.
// 512 blocks x 256 threads, 16 rows/block.
// ---------------------------------------------------------------------------
__global__ __launch_bounds__(256, 4)
void reduce_kernel(const float* __restrict__ acc_part, const float* __restrict__ l_part,
                   const float* __restrict__ Wc, const float* __restrict__ bcv,
                   float* __restrict__ out, int split) {
    __shared__ __align__(16) float hu[16][OUT_F + 4];
    const int t = threadIdx.x;
    const int i0 = blockIdx.x * 16;
    const int row = t >> 4, cg = t & 15;

    f32x4 v0 = {0.f, 0.f, 0.f, 0.f}, v1 = {0.f, 0.f, 0.f, 0.f};
    float l = 0.f;
    for (int s = 0; s < split; ++s) {
        const float* ap = acc_part + (size_t)s * N * OUT_F + (size_t)(i0 + row) * OUT_F + cg * 8;
        v0 += *(const f32x4*)ap;
        v1 += *(const f32x4*)(ap + 4);
        l += l_part[(size_t)s * N + i0 + row];
    }
    float inv = 1.f / l;
    #pragma unroll
    for (int e = 0; e < 4; ++e) {
        float x0 = v0[e] * inv; x0 = x0 > 0.f ? x0 : (__expf(x0) - 1.f);
        float x1 = v1[e] * inv; x1 = x1 > 0.f ? x1 : (__expf(x1) - 1.f);
        hu[row][cg * 8 + e] = x0;
        hu[row][cg * 8 + 4 + e] = x1;
    }
    __syncthreads();

    if (t < 16 * NCLS) {
        int rr = t / NCLS, cls = t - rr * NCLS;
        const f32x4* hurow = (const f32x4*)&hu[rr][0];
        const f32x4* wcrow = (const f32x4*)(Wc + cls * OUT_F);
        float sum = bcv[cls];
        #pragma unroll 8
        for (int c4 = 0; c4 < OUT_F / 4; ++c4) {
            f32x4 hv = hurow[c4];
            f32x4 wv = wcrow[c4];
            sum += hv[0] * wv[0] + hv[1] * wv[1] + hv[2] * wv[2] + hv[3] * wv[3];
        }
        out[(size_t)(i0 + rr) * NCLS + cls] = sum;
    }
}

// ---------------------------------------------------------------------------
extern "C" void kernel_launch(void* const* d_in, const int* in_sizes, int n_in,
                              void* d_out, int out_size, void* d_ws, size_t ws_size,
                              hipStream_t stream) {
    const float* h    = (const float*)d_in[0];
    const int*   dist = (const int*)d_in[1];
    const float* W    = (const float*)d_in[2];
    const float* a    = (const float*)d_in[3];
    const float* Wc   = (const float*)d_in[4];
    const float* bc   = (const float*)d_in[5];
    float* out = (float*)d_out;

    char* ws = (char*)d_ws;
    size_t off = 0;
    short* WhT  = (short*)(ws + off); off += (size_t)OUT_F * N * 2;     // 2 MB
    short* WThi = (short*)(ws + off); off += (size_t)IN_F * OUT_F * 2;  // 128 KB
    short* WTlo = (short*)(ws + off); off += (size_t)IN_F * OUT_F * 2;  // 128 KB
    float* Wh1  = (float*)(ws + off); off += (size_t)N * 4;
    float* Wh2  = (float*)(ws + off); off += (size_t)N * 4;
    unsigned* mask = (unsigned*)(ws + off); off += (size_t)N * (N / 32) * 4; // 8 MB

    float* acc_part = (float*)(ws + off); off += (size_t)SPLIT * N * OUT_F * 4; // 16 MB
    float* l_part   = (float*)(ws + off);

    hipLaunchKernelGGL(mask_kernel, dim3(N * (N / 32) / 256), dim3(256), 0, stream,
                       dist, mask);
    hipLaunchKernelGGL(split_w_kernel, dim3(256), dim3(256), 0, stream, W, WThi, WTlo);
    hipLaunchKernelGGL(wh_kernel, dim3(N / WH_ROWS), dim3(256), 0, stream,
                       h, WThi, WTlo, a, WhT, Wh1, Wh2);
    hipLaunchKernelGGL(attn_kernel, dim3(256 * SPLIT), dim3(256), 0, stream,
                       mask, WhT, Wh1, Wh2, acc_part, l_part);
    hipLaunchKernelGGL(reduce_kernel, dim3(N / 16), dim3(256), 0, stream,
                       acc_part, l_part, Wc, bc, out, SPLIT);
}